// Round 1
// baseline (103.854 us; speedup 1.0000x reference)
//
#include <hip/hip_runtime.h>
#include <math.h>

// Shapes: S=4 B=8 N=2048 K=16 D=32 H=128; rows SBN=65536, rows/sb=2048.
// Single fused kernel: 64 n-rows per block, 1024 blocks = exactly 4/CU.
// LDS 30.5 KB -> 4 blocks/CU resident (was 48 KB -> 3/CU + 25% dispatch tail).
typedef _Float16 half_t;
typedef __attribute__((ext_vector_type(8))) _Float16 half8;

#define EXP2F(x) __builtin_amdgcn_exp2f(x)
#define RCPF(x)  __builtin_amdgcn_rcpf(x)
#define C_SCALE 2.8853900817779268f   // 2*log2(e): tanh(z)=1-2/(1+2^(c*z))

__global__ __launch_bounds__(256, 4) void fused_kernel(
    const float* __restrict__ x, const float* __restrict__ mu,
    const float* __restrict__ tau, const float* __restrict__ W1,
    const float* __restrict__ b1, const float* __restrict__ W2,
    float* __restrict__ out) {
  __shared__ __align__(16) float  sX[64][36];     // c*x tile (pad 36)
  __shared__ __align__(16) half_t sEx[64][136];   // f16 ex tile (272B rows)
  __shared__ __align__(16) half_t sEk[16][136];
  __shared__ __align__(16) half_t sW2[128];

  int t = threadIdx.x;
  int row0 = blockIdx.x * 64;
  int sb = row0 >> 11;

  // ---- stage c*x tile: 64x32 = 512 float4, coalesced (C folded into x, not W)
  const float4* x4 = (const float4*)(x + (size_t)row0 * 32);
#pragma unroll
  for (int i = 0; i < 2; ++i) {
    int j = i * 256 + t;                 // 0..511
    int n = j >> 3, d4 = j & 7;
    float4 v = x4[j];
    v.x *= C_SCALE; v.y *= C_SCALE; v.z *= C_SCALE; v.w *= C_SCALE;
    *(float4*)&sX[n][d4 * 4] = v;
  }
  // ---- stage w2h = f16(-2*W2)
  if (t < 16) {
    float4 a = ((const float4*)W2)[2 * t];
    float4 b = ((const float4*)W2)[2 * t + 1];
    half8 hv;
    hv[0] = (half_t)(-2.f * a.x); hv[1] = (half_t)(-2.f * a.y);
    hv[2] = (half_t)(-2.f * a.z); hv[3] = (half_t)(-2.f * a.w);
    hv[4] = (half_t)(-2.f * b.x); hv[5] = (half_t)(-2.f * b.y);
    hv[6] = (half_t)(-2.f * b.z); hv[7] = (half_t)(-2.f * b.w);
    *(half8*)&sW2[t * 8] = hv;
  }
  __syncthreads();

  // ---- phase 1: hx GEMM -> exp2 -> f16 LDS tile. Wx read from global
  //      (16 KB, L1-resident; replaces 17 KB LDS + 4-way-conflicted ds_reads)
  {
    int hg = t & 15, rg = t >> 4;        // 16 h-octs x 16 row-quads
    int h0 = hg * 8, r0 = rg * 4;
    float acc[4][8];
#pragma unroll
    for (int j = 0; j < 4; ++j)
#pragma unroll
      for (int l = 0; l < 8; ++l) acc[j][l] = 0.f;
    const float* Wp = W1 + h0;
#pragma unroll 4
    for (int d = 0; d < 32; ++d) {
      float4 wa = *(const float4*)(Wp + d * 128);
      float4 wb = *(const float4*)(Wp + d * 128 + 4);
      float w[8] = {wa.x, wa.y, wa.z, wa.w, wb.x, wb.y, wb.z, wb.w};
#pragma unroll
      for (int j = 0; j < 4; ++j) {
        float xv = sX[r0 + j][d];        // broadcast among 16 lanes
#pragma unroll
        for (int l = 0; l < 8; ++l) acc[j][l] = fmaf(xv, w[l], acc[j][l]);
      }
    }
#pragma unroll
    for (int j = 0; j < 4; ++j) {
      half8 hv;
#pragma unroll
      for (int l = 0; l < 8; ++l) hv[l] = (half_t)EXP2F(acc[j][l]);
      *(half8*)&sEx[r0 + j][h0] = hv;
    }
  }

  // ---- ek: per-block recompute (prep kernel fused) straight into sEk.
  //      ek[k][h] = f16(exp2(c*(mu[k,:]@Wm[:,h] + tau[k,:]@Wt[:,h] + b1[h])))
  //      Same fma order as the old prep kernel -> bit-identical ek.
  {
    int k = t >> 4, h0 = (t & 15) * 8;
    const float4* mu4  = (const float4*)(mu  + ((size_t)sb * 16 + k) * 32);
    const float4* tau4 = (const float4*)(tau + ((size_t)sb * 16 + k) * 32);
    float acc[8];
    {
      float4 ba = *(const float4*)(b1 + h0);
      float4 bb = *(const float4*)(b1 + h0 + 4);
      acc[0] = ba.x; acc[1] = ba.y; acc[2] = ba.z; acc[3] = ba.w;
      acc[4] = bb.x; acc[5] = bb.y; acc[6] = bb.z; acc[7] = bb.w;
    }
    const float* Wm = W1 + 32 * 128 + h0;
    const float* Wt = W1 + 64 * 128 + h0;
#pragma unroll 2
    for (int d4 = 0; d4 < 8; ++d4) {
      float4 m4 = mu4[d4], t4 = tau4[d4];
      float mv4[4] = {m4.x, m4.y, m4.z, m4.w};
      float tv4[4] = {t4.x, t4.y, t4.z, t4.w};
#pragma unroll
      for (int dd = 0; dd < 4; ++dd) {
        int d = d4 * 4 + dd;
        float4 wma = *(const float4*)(Wm + d * 128);
        float4 wmb = *(const float4*)(Wm + d * 128 + 4);
        float4 wta = *(const float4*)(Wt + d * 128);
        float4 wtb = *(const float4*)(Wt + d * 128 + 4);
        float wm[8] = {wma.x, wma.y, wma.z, wma.w, wmb.x, wmb.y, wmb.z, wmb.w};
        float wt[8] = {wta.x, wta.y, wta.z, wta.w, wtb.x, wtb.y, wtb.z, wtb.w};
        float mv = mv4[dd], tv = tv4[dd];
#pragma unroll
        for (int l = 0; l < 8; ++l) {
          acc[l] = fmaf(mv, wm[l], acc[l]);
          acc[l] = fmaf(tv, wt[l], acc[l]);
        }
      }
    }
    half8 hv;
#pragma unroll
    for (int l = 0; l < 8; ++l) hv[l] = (half_t)EXP2F(C_SCALE * acc[l]);
    *(half8*)&sEk[k][h0] = hv;
  }
  __syncthreads();

  // ---- phase 2: hot loop, 2 rows x 2 k per thread ----
  int kg = t & 7, rg = t >> 3;           // rg 0..31
  int r0 = rg * 2, k0 = kg * 2;
  float a00 = 0.f, a01 = 0.f, a10 = 0.f, a11 = 0.f;
#pragma unroll 2
  for (int h8 = 0; h8 < 16; ++h8) {
    half8 ex0 = *(const half8*)&sEx[r0][h8 * 8];
    half8 ex1 = *(const half8*)&sEx[r0 + 1][h8 * 8];
    half8 ekv0 = *(const half8*)&sEk[k0][h8 * 8];
    half8 ekv1 = *(const half8*)&sEk[k0 + 1][h8 * 8];
    half8 wv = *(const half8*)&sW2[h8 * 8];
#pragma unroll
    for (int j = 0; j < 8; ++j) {
      float e0 = (float)ex0[j], e1 = (float)ex1[j];
      float f0 = (float)ekv0[j], f1 = (float)ekv1[j];
      float w = (float)wv[j];
      a00 = fmaf(w, RCPF(fmaf(e0, f0, 1.0f)), a00);
      a01 = fmaf(w, RCPF(fmaf(e0, f1, 1.0f)), a01);
      a10 = fmaf(w, RCPF(fmaf(e1, f0, 1.0f)), a10);
      a11 = fmaf(w, RCPF(fmaf(e1, f1, 1.0f)), a11);
    }
  }

  // ---- softmax over k: 2 k in-thread x 8 kg-lanes (shuffle width 8) ----
  const float l2e = 1.4426950408889634f;
  {
    float m = fmaxf(a00, a01);
#pragma unroll
    for (int s = 1; s < 8; s <<= 1) m = fmaxf(m, __shfl_xor(m, s, 8));
    float p0 = EXP2F((a00 - m) * l2e), p1 = EXP2F((a01 - m) * l2e);
    float sum = p0 + p1;
#pragma unroll
    for (int s = 1; s < 8; s <<= 1) sum += __shfl_xor(sum, s, 8);
    float inv = RCPF(sum);
    float2 o = make_float2(p0 * inv, p1 * inv);
    *(float2*)&out[(size_t)(row0 + r0) * 16 + k0] = o;
  }
  {
    float m = fmaxf(a10, a11);
#pragma unroll
    for (int s = 1; s < 8; s <<= 1) m = fmaxf(m, __shfl_xor(m, s, 8));
    float p0 = EXP2F((a10 - m) * l2e), p1 = EXP2F((a11 - m) * l2e);
    float sum = p0 + p1;
#pragma unroll
    for (int s = 1; s < 8; s <<= 1) sum += __shfl_xor(sum, s, 8);
    float inv = RCPF(sum);
    float2 o = make_float2(p0 * inv, p1 * inv);
    *(float2*)&out[(size_t)(row0 + r0 + 1) * 16 + k0] = o;
  }
}

// ---------------------------------------------------------------------------
extern "C" void kernel_launch(void* const* d_in, const int* in_sizes, int n_in,
                              void* d_out, int out_size, void* d_ws, size_t ws_size,
                              hipStream_t stream) {
  const float* x   = (const float*)d_in[0];
  const float* mu  = (const float*)d_in[1];
  const float* tau = (const float*)d_in[2];
  const float* W1  = (const float*)d_in[3];
  const float* b1  = (const float*)d_in[4];
  const float* W2  = (const float*)d_in[5];
  // b2 (d_in[6]) and sum(W2) are k-uniform -> cancelled by softmax.
  float* out = (float*)d_out;
  (void)in_sizes; (void)n_in; (void)out_size; (void)d_ws; (void)ws_size;

  fused_kernel<<<1024, 256, 0, stream>>>(x, mu, tau, W1, b1, W2, out);
}